// Round 15
// baseline (160.110 us; speedup 1.0000x reference)
//
#include <hip/hip_runtime.h>

#define NN 50000            // nodes
#define NE 800000           // edges
#define NF 128              // input features
#define NH 64               // hidden
#define NG 256              // graphs
#define NB 196              // buckets of 256 dst nodes
#define NC 196              // chunks: ceil(NE/CH)
#define CH 4096             // edges per partition block
#define CELL 80             // per-(chunk,bucket) capacity
#define CAP 5120            // per-bucket CSR capacity
#define NGB 782             // gemm blocks: ceil(NN/64)

typedef __attribute__((ext_vector_type(8))) short bf16x8;
typedef __attribute__((ext_vector_type(4))) float f32x4;

static __device__ __forceinline__ unsigned short f2bf(float f) {
    union { float f; unsigned u; } v; v.f = f;
    unsigned r = v.u + 0x7FFF + ((v.u >> 16) & 1);   // RNE
    return (unsigned short)(r >> 16);
}
static __device__ __forceinline__ float lo16(unsigned u) {
    return __uint_as_float(u << 16);
}
static __device__ __forceinline__ float hi16(unsigned u) {
    return __uint_as_float(u & 0xFFFF0000u);
}
static __device__ __forceinline__ unsigned pack2(float a, float b) {
    return (unsigned)f2bf(a) | ((unsigned)f2bf(b) << 16);
}

// ---------------------------------------------------------------- fused: psum-zero + partition + gemm1
__global__ __launch_bounds__(256) void prep_gemm(const int* __restrict__ ei,
                                                 int* __restrict__ histg,
                                                 int2* __restrict__ ebuf,
                                                 const float* __restrict__ X,
                                                 const float* __restrict__ W,
                                                 unsigned short* __restrict__ Y,
                                                 float* __restrict__ psum) {
    __shared__ __align__(16) char smem[35840];
    const int t = threadIdx.x;

    if (blockIdx.x < NC) {
        // ---------------- partition path ----------------
        int* hist = (int*)smem;
        int* incl = hist + 256;
        int* lcur = incl + 256;
        int2* lpairs = (int2*)(smem + 3072);
        const int c = blockIdx.x;
        const int c0 = c * CH;

        hist[t] = 0;
        __syncthreads();

        int2 loc[16];
#pragma unroll
        for (int j = 0; j < 16; ++j) {
            int e = c0 + j * 256 + t;
            int s = -1, d = -1;
            if (e < NE) {
                s = ei[e]; d = ei[NE + e];
                atomicAdd(&hist[d >> 8], 1);
            }
            loc[j] = make_int2(s, d);
        }
        __syncthreads();

        int v = hist[t];
        incl[t] = v;
        __syncthreads();
        for (int off = 1; off < 256; off <<= 1) {
            int u = (t >= off) ? incl[t - off] : 0;
            __syncthreads();
            incl[t] += u;
            __syncthreads();
        }
        lcur[t] = incl[t] - v;
        if (t < NB) histg[c * NB + t] = v;
        __syncthreads();

#pragma unroll
        for (int j = 0; j < 16; ++j) {
            int d = loc[j].y;
            if (d >= 0) {
                int p = atomicAdd(&lcur[d >> 8], 1);
                lpairs[p] = loc[j];
            }
        }
        __syncthreads();

        const int total = incl[255];
        for (int p = t; p < total; p += 256) {
            int2 pr = lpairs[p];
            int b = pr.y >> 8;
            int i = p - (incl[b] - hist[b]);
            ebuf[(b * NC + c) * CELL + i] = pr;
        }
    } else {
        // ---------------- gemm1 path (no dis dependency) ----------------
        const int gb = blockIdx.x - NC;
        if (gb < 16)   // zero psum
            *(float4*)&psum[gb * 1024 + t * 4] = make_float4(0.f, 0.f, 0.f, 0.f);

        unsigned short* Xs = (unsigned short*)smem;       // 64*136 bf16
        unsigned int* Wt = (unsigned int*)(smem + 17408); // 64*68 packed
        const int base = gb * 64;

        for (int i = t * 4; i < 64 * 128; i += 1024) {
            int node = i >> 7, k = i & 127;
            int gn = base + node; if (gn >= NN) gn = NN - 1;
            float4 v = *(const float4*)&X[(size_t)gn * 128 + k];
            ushort4 o = { f2bf(v.x), f2bf(v.y), f2bf(v.z), f2bf(v.w) };
            *(ushort4*)&Xs[node * 136 + k] = o;
        }
        for (int idx = t; idx < 64 * 64; idx += 256) {
            int n = idx & 63, kp = idx >> 6;
            float w0 = W[(2 * kp) * 64 + n];
            float w1 = W[(2 * kp + 1) * 64 + n];
            Wt[n * 68 + kp] = (unsigned)f2bf(w0) | ((unsigned)f2bf(w1) << 16);
        }
        __syncthreads();

        const int w = t >> 6;
        const int lane = t & 63;
        const int l15 = lane & 15;
        const int quad = lane >> 4;
        f32x4 acc[4] = {{0.f,0.f,0.f,0.f},{0.f,0.f,0.f,0.f},{0.f,0.f,0.f,0.f},{0.f,0.f,0.f,0.f}};
#pragma unroll
        for (int kk = 0; kk < 4; ++kk) {
            const bf16x8 a = *(const bf16x8*)&Xs[(w * 16 + l15) * 136 + quad * 8 + kk * 32];
#pragma unroll
            for (int nt = 0; nt < 4; ++nt) {
                const bf16x8 b = *(const bf16x8*)&Wt[(nt * 16 + l15) * 68 + quad * 4 + kk * 16];
                acc[nt] = __builtin_amdgcn_mfma_f32_16x16x32_bf16(a, b, acc[nt], 0, 0, 0);
            }
        }
        const int r0 = base + w * 16 + quad * 4;
#pragma unroll
        for (int reg = 0; reg < 4; ++reg) {
            const int row = r0 + reg;
            if (row < NN) {
#pragma unroll
                for (int nt = 0; nt < 4; ++nt)
                    Y[(size_t)row * 64 + nt * 16 + l15] = f2bf(acc[nt][reg]);
            }
        }
    }
}

// ---------------------------------------------------------------- level-2: CSR + dis + fold dis into h + degree-sorted perm
__global__ __launch_bounds__(256) void build_csr(const int2* __restrict__ ebuf,
                                                 const int* __restrict__ histg,
                                                 const int* __restrict__ batch,
                                                 int2* __restrict__ row_range,
                                                 float* __restrict__ dis,
                                                 int* __restrict__ csr_src,
                                                 int* __restrict__ perm,
                                                 unsigned short* __restrict__ h) {
    const int b = blockIdx.x, t = threadIdx.x;
    const int e0 = b * CAP;
    const int node = b * 256 + t;
    __shared__ int coff[256];
    __shared__ int deg_l[256];
    __shared__ int pre[256];
    __shared__ int cur[256];
    __shared__ float sdis[256];
    __shared__ int2 lpairs[CAP];
    __shared__ int lsrc[CAP];

    int cv = (t < NB) ? histg[t * NB + b] : 0;
    coff[t] = cv;
    __syncthreads();
    for (int off = 1; off < 256; off <<= 1) {
        int u = (t >= off) ? coff[t - off] : 0;
        __syncthreads();
        coff[t] += u;
        __syncthreads();
    }
    if (cv > 0) {
        const int2* src = &ebuf[(b * NC + t) * CELL];
        int dst = coff[t] - cv;
        for (int i = 0; i < cv; ++i)
            lpairs[dst + i] = src[i];
    }
    deg_l[t] = (node < NN) ? 1 : 0;   // self-loop
    __syncthreads();

    const int total = coff[255];
    for (int i = t; i < total; i += 256)
        atomicAdd(&deg_l[lpairs[i].y & 255], 1);
    __syncthreads();

    int v = deg_l[t];
    pre[t] = v;
    __syncthreads();
    for (int off = 1; off < 256; off <<= 1) {
        int u = (t >= off) ? pre[t - off] : 0;
        __syncthreads();
        pre[t] += u;
        __syncthreads();
    }
    int excl = pre[t] - v;
    cur[t] = 1;                        // slot 0 = self-loop
    float dv = 0.f;
    if (node < NN) {
        lsrc[excl] = node;
        row_range[node] = make_int2(e0 + excl, e0 + pre[t]);
        dv = rsqrtf((float)v);         // v = deg+1
        dis[node] = dv;
    }
    sdis[t] = dv;
    __syncthreads();
    for (int i = t; i < total; i += 256) {
        int2 p = lpairs[i];
        int d = p.y & 255;
        int pos = (pre[d] - deg_l[d]) + atomicAdd(&cur[d], 1);
        lsrc[pos] = p.x;
    }
    __syncthreads();
    const int tot_all = pre[255];
    for (int i = t; i < tot_all; i += 256)
        csr_src[e0 + i] = lsrc[i];
    __syncthreads();

    // ---- degree-sorted perm: counting sort of 256 nodes by (graph, deg) ----
    // key = min(gb,2)*64 + min(deg,63) in [0,191]; invalid nodes key=192
    // (sorted to bucket end). Keeps batch non-decreasing in perm order, so
    // agg_pool's segment reduce stays grouped. Reuses cur/pre/deg_l.
    int key;
    if (node < NN) {
        int gb_ = batch[node] - batch[b * 256];
        if (gb_ > 2) gb_ = 2;
        int dk = v - 1; if (dk > 63) dk = 63;
        key = gb_ * 64 + dk;
    } else key = 192;
    cur[t] = 0; deg_l[t] = 0;
    __syncthreads();
    atomicAdd(&cur[key], 1);
    __syncthreads();
    int hv = cur[t];
    pre[t] = hv;
    __syncthreads();
    for (int off = 1; off < 256; off <<= 1) {
        int u = (t >= off) ? pre[t - off] : 0;
        __syncthreads();
        pre[t] += u;
        __syncthreads();
    }
    int pos = (pre[key] - cur[key]) + atomicAdd(&deg_l[key], 1);
    perm[b * 256 + pos] = node;        // node >= NN acts as sentinel

    // ---- fold dis into h rows (bufA from prep_gemm): coalesced r/m/w ----
    const int rl0 = t >> 3;
    const int d8 = (t & 7) * 8;
#pragma unroll
    for (int c = 0; c < 8; ++c) {
        const int rl = c * 32 + rl0;
        const int n2 = b * 256 + rl;
        if (n2 < NN) {
            const float dd = sdis[rl];
            uint4 u = *(uint4*)&h[(size_t)n2 * 64 + d8];
            uint4 o;
            o.x = pack2(lo16(u.x) * dd, hi16(u.x) * dd);
            o.y = pack2(lo16(u.y) * dd, hi16(u.y) * dd);
            o.z = pack2(lo16(u.z) * dd, hi16(u.z) * dd);
            o.w = pack2(lo16(u.w) * dd, hi16(u.w) * dd);
            *(uint4*)&h[(size_t)n2 * 64 + d8] = o;
        }
    }
}

// ---------------------------------------------------------------- sub-group gather core (pre-scaled rows)
static __device__ __forceinline__ void acc8(float* acc, const uint4 u) {
    acc[0] += lo16(u.x); acc[1] += hi16(u.x);
    acc[2] += lo16(u.y); acc[3] += hi16(u.y);
    acc[4] += lo16(u.z); acc[5] += hi16(u.z);
    acc[6] += lo16(u.w); acc[7] += hi16(u.w);
}

static __device__ __forceinline__ void gather_rows(const unsigned short* __restrict__ h,
                                                   const int* __restrict__ csr_src,
                                                   int lo, int hi, int p8, float* acc) {
    int i = lo;
    for (; i + 4 <= hi; i += 4) {
        const int i0 = csr_src[i];
        const int i1 = csr_src[i + 1];
        const int i2 = csr_src[i + 2];
        const int i3 = csr_src[i + 3];
        const uint4 u0 = *(const uint4*)&h[(i0 << 6) + p8];
        const uint4 u1 = *(const uint4*)&h[(i1 << 6) + p8];
        const uint4 u2 = *(const uint4*)&h[(i2 << 6) + p8];
        const uint4 u3 = *(const uint4*)&h[(i3 << 6) + p8];
        acc8(acc, u0); acc8(acc, u1); acc8(acc, u2); acc8(acc, u3);
    }
    for (; i + 2 <= hi; i += 2) {
        const int i0 = csr_src[i];
        const int i1 = csr_src[i + 1];
        const uint4 u0 = *(const uint4*)&h[(i0 << 6) + p8];
        const uint4 u1 = *(const uint4*)&h[(i1 << 6) + p8];
        acc8(acc, u0); acc8(acc, u1);
    }
    if (i < hi) {
        const int i0 = csr_src[i];
        acc8(acc, *(const uint4*)&h[(i0 << 6) + p8]);
    }
}

// ---------------------------------------------------------------- agg1 + gemm2 fused (perm order)
__global__ __launch_bounds__(256) void agg_gemv(const unsigned short* __restrict__ h,
                                                const int2* __restrict__ row_range,
                                                const int* __restrict__ csr_src,
                                                const float* __restrict__ dis,
                                                const int* __restrict__ perm,
                                                const float* __restrict__ b1,
                                                const float* __restrict__ W2,
                                                unsigned short* __restrict__ g) {
    __shared__ unsigned short W2b[64 * 72];  // [n][k] bf16
    __shared__ unsigned short A[32 * 72];    // [m][k] bf16
    __shared__ int pnode[32];
    __shared__ float pdis[32];
    const int t = threadIdx.x;
    for (int idx = t; idx < 64 * 32; idx += 256) {
        int n = idx & 63, kp = idx >> 6;
        unsigned short w0 = f2bf(W2[(2 * kp) * 64 + n]);
        unsigned short w1 = f2bf(W2[(2 * kp + 1) * 64 + n]);
        *(unsigned*)&W2b[n * 72 + 2 * kp] = (unsigned)w0 | ((unsigned)w1 << 16);
    }

    const int base = blockIdx.x * 32;
    const int nloc = t >> 3;
    const int p8 = (t & 7) * 8;
    const int n = perm[base + nloc];
    float acc[8] = {};
    float dn = 0.f;
    if (n < NN) {
        const int2 rr = row_range[n];
        gather_rows(h, csr_src, rr.x, rr.y, p8, acc);
        dn = dis[n];
        const float4 bv0 = *(const float4*)&b1[p8];
        const float4 bv1 = *(const float4*)&b1[p8 + 4];
        acc[0] = fmaxf(acc[0] * dn + bv0.x, 0.f);
        acc[1] = fmaxf(acc[1] * dn + bv0.y, 0.f);
        acc[2] = fmaxf(acc[2] * dn + bv0.z, 0.f);
        acc[3] = fmaxf(acc[3] * dn + bv0.w, 0.f);
        acc[4] = fmaxf(acc[4] * dn + bv1.x, 0.f);
        acc[5] = fmaxf(acc[5] * dn + bv1.y, 0.f);
        acc[6] = fmaxf(acc[6] * dn + bv1.z, 0.f);
        acc[7] = fmaxf(acc[7] * dn + bv1.w, 0.f);
    }
    if ((t & 7) == 0) { pnode[nloc] = n; pdis[nloc] = dn; }
    uint4 pk;
    pk.x = pack2(acc[0], acc[1]);
    pk.y = pack2(acc[2], acc[3]);
    pk.z = pack2(acc[4], acc[5]);
    pk.w = pack2(acc[6], acc[7]);
    *(uint4*)&A[nloc * 72 + p8] = pk;
    __syncthreads();

    const int w = t >> 6;
    const int lane = t & 63;
    const int l15 = lane & 15;
    const int quad = lane >> 4;
    const int mt = w & 1;
    const int nq = (w >> 1) * 2;
    const bf16x8 a0 = *(const bf16x8*)&A[(mt * 16 + l15) * 72 + quad * 8];
    const bf16x8 a1 = *(const bf16x8*)&A[(mt * 16 + l15) * 72 + 32 + quad * 8];
    const bf16x8 b00 = *(const bf16x8*)&W2b[(nq * 16 + l15) * 72 + quad * 8];
    const bf16x8 b01 = *(const bf16x8*)&W2b[(nq * 16 + l15) * 72 + 32 + quad * 8];
    const bf16x8 b10 = *(const bf16x8*)&W2b[((nq + 1) * 16 + l15) * 72 + quad * 8];
    const bf16x8 b11 = *(const bf16x8*)&W2b[((nq + 1) * 16 + l15) * 72 + 32 + quad * 8];
    f32x4 c0 = {0.f, 0.f, 0.f, 0.f}, c1 = {0.f, 0.f, 0.f, 0.f};
    c0 = __builtin_amdgcn_mfma_f32_16x16x32_bf16(a0, b00, c0, 0, 0, 0);
    c0 = __builtin_amdgcn_mfma_f32_16x16x32_bf16(a1, b01, c0, 0, 0, 0);
    c1 = __builtin_amdgcn_mfma_f32_16x16x32_bf16(a0, b10, c1, 0, 0, 0);
    c1 = __builtin_amdgcn_mfma_f32_16x16x32_bf16(a1, b11, c1, 0, 0, 0);
    const int mrow0 = mt * 16 + quad * 4;
#pragma unroll
    for (int reg = 0; reg < 4; ++reg) {
        const int row = pnode[mrow0 + reg];
        if (row < NN) {
            const float dd = pdis[mrow0 + reg];
            g[(size_t)row * 64 + nq * 16 + l15] = f2bf(c0[reg] * dd);
            g[(size_t)row * 64 + (nq + 1) * 16 + l15] = f2bf(c1[reg] * dd);
        }
    }
}

// ---------------------------------------------------------------- agg2 + pooling fused (perm order)
__global__ __launch_bounds__(256) void agg_pool(const unsigned short* __restrict__ h,
                                                const int2* __restrict__ row_range,
                                                const int* __restrict__ csr_src,
                                                const float* __restrict__ dis,
                                                const int* __restrict__ perm,
                                                const float* __restrict__ bias,
                                                const int* __restrict__ batch,
                                                float* __restrict__ psum) {
    __shared__ float rowsL[32 * 68];
    __shared__ int nb[32];
    const int t = threadIdx.x;
    const int nloc = t >> 3;
    const int n = perm[blockIdx.x * 32 + nloc];
    const int p8 = (t & 7) * 8;
    if ((t & 7) == 0) nb[nloc] = (n < NN) ? batch[n] : -1;
    if (n < NN) {
        const int2 rr = row_range[n];
        float acc[8] = {};
        gather_rows(h, csr_src, rr.x, rr.y, p8, acc);
        const float dn = dis[n];
        const float4 bv0 = *(const float4*)&bias[p8];
        const float4 bv1 = *(const float4*)&bias[p8 + 4];
        float4 r0, r1;
        r0.x = fmaxf(acc[0] * dn + bv0.x, 0.f);
        r0.y = fmaxf(acc[1] * dn + bv0.y, 0.f);
        r0.z = fmaxf(acc[2] * dn + bv0.z, 0.f);
        r0.w = fmaxf(acc[3] * dn + bv0.w, 0.f);
        r1.x = fmaxf(acc[4] * dn + bv1.x, 0.f);
        r1.y = fmaxf(acc[5] * dn + bv1.y, 0.f);
        r1.z = fmaxf(acc[6] * dn + bv1.z, 0.f);
        r1.w = fmaxf(acc[7] * dn + bv1.w, 0.f);
        *(float4*)&rowsL[nloc * 68 + p8] = r0;
        *(float4*)&rowsL[nloc * 68 + p8 + 4] = r1;
    }
    __syncthreads();
    if (t < 64) {
        float s = 0.f; int curg = -2;
        for (int r = 0; r < 32; ++r) {
            const int gg = nb[r];                 // wave-uniform
            if (gg != curg) {
                if (curg >= 0) atomicAdd(&psum[curg * 64 + t], s);
                s = 0.f; curg = gg;
            }
            if (gg >= 0) s += rowsL[r * 68 + t];
        }
        if (curg >= 0) atomicAdd(&psum[curg * 64 + t], s);
    }
}

// ---------------------------------------------------------------- head: mean + MLP
__global__ __launch_bounds__(64) void head_kernel(const float* __restrict__ psum,
                                                  const int* __restrict__ batch,
                                                  const float* __restrict__ Wm1,
                                                  const float* __restrict__ bm1,
                                                  const float* __restrict__ Wm2,
                                                  const float* __restrict__ bm2,
                                                  float* __restrict__ out) {
    const int g = blockIdx.x;
    const int t = threadIdx.x;
    int lo = 0, hi = NN;
    while (lo < hi) { int m = (lo + hi) >> 1; if (batch[m] < g) lo = m + 1; else hi = m; }
    const int s = lo;
    hi = NN;
    while (lo < hi) { int m = (lo + hi) >> 1; if (batch[m] < g + 1) lo = m + 1; else hi = m; }
    const int cnt = lo - s;

    __shared__ float pl[64];
    pl[t] = psum[g * 64 + t] / (float)(cnt > 0 ? cnt : 1);
    __syncthreads();
    float z = bm1[t];
#pragma unroll 8
    for (int k = 0; k < 64; ++k)
        z += pl[k] * Wm1[k * 64 + t];
    z = fmaxf(z, 0.f);
    float y = z * Wm2[t];
    for (int off = 32; off; off >>= 1) y += __shfl_down(y, off);
    if (t == 0) out[g] = y + bm2[0];
}

// ---------------------------------------------------------------- launch
extern "C" void kernel_launch(void* const* d_in, const int* in_sizes, int n_in,
                              void* d_out, int out_size, void* d_ws, size_t ws_size,
                              hipStream_t stream) {
    const float* x   = (const float*)d_in[0];
    const int*   ei  = (const int*)d_in[1];
    const int*   bat = (const int*)d_in[2];
    const float* W1  = (const float*)d_in[3];
    const float* b1  = (const float*)d_in[4];
    const float* W2  = (const float*)d_in[5];
    const float* b2  = (const float*)d_in[6];
    const float* Wm1 = (const float*)d_in[7];
    const float* bm1 = (const float*)d_in[8];
    const float* Wm2 = (const float*)d_in[9];
    const float* bm2 = (const float*)d_in[10];
    float* out = (float*)d_out;

    char* w = (char*)d_ws;
    int*            histg     = (int*)           (w + 0);          //   153664 B
    int2*           row_range = (int2*)          (w + 153664);     //   400000 B
    float*          dis       = (float*)         (w + 553664);     //   200000 B
    int*            csr_src   = (int*)           (w + 753664);     //  4014080 B
    int2*           ebuf      = (int2*)          (w + 4767744);    // 24586240 B
    unsigned short* bufA      = (unsigned short*)(w + 29353984);   //  6400000 B
    unsigned short* bufB      = (unsigned short*)(w + 35753984);   //  6400000 B
    float*          psum      = (float*)         (w + 42153984);   //    65536 B
    int*            perm      = (int*)           (w + 42219520);   //   200704 B (NB*256)

    prep_gemm <<<NC + NGB, 256, 0, stream>>>(ei, histg, ebuf, x, W1, bufA, psum);
    build_csr <<<NB, 256, 0, stream>>>(ebuf, histg, bat, row_range, dis, csr_src, perm, bufA);
    agg_gemv  <<<(NN + 31) / 32, 256, 0, stream>>>(bufA, row_range, csr_src, dis, perm, b1, W2, bufB);
    agg_pool  <<<(NN + 31) / 32, 256, 0, stream>>>(bufB, row_range, csr_src, dis, perm, b2, bat, psum);
    head_kernel<<<NG, 64, 0, stream>>>(psum, bat, Wm1, bm1, Wm2, bm2, out);
}

// Round 16
// 157.751 us; speedup vs baseline: 1.0150x; 1.0150x over previous
//
#include <hip/hip_runtime.h>

#define NN 50000            // nodes
#define NE 800000           // edges
#define NF 128              // input features
#define NH 64               // hidden
#define NG 256              // graphs
#define NB 196              // buckets of 256 dst nodes
#define NC 196              // chunks: ceil(NE/CH)
#define CH 4096             // edges per partition block
#define CELL 80             // per-(chunk,bucket) capacity
#define CAP 5120            // per-bucket CSR capacity
#define NGB 782             // gemm blocks: ceil(NN/64)

typedef __attribute__((ext_vector_type(8))) short bf16x8;
typedef __attribute__((ext_vector_type(4))) float f32x4;

static __device__ __forceinline__ unsigned short f2bf(float f) {
    union { float f; unsigned u; } v; v.f = f;
    unsigned r = v.u + 0x7FFF + ((v.u >> 16) & 1);   // RNE
    return (unsigned short)(r >> 16);
}
static __device__ __forceinline__ float lo16(unsigned u) {
    return __uint_as_float(u << 16);
}
static __device__ __forceinline__ float hi16(unsigned u) {
    return __uint_as_float(u & 0xFFFF0000u);
}
static __device__ __forceinline__ unsigned pack2(float a, float b) {
    return (unsigned)f2bf(a) | ((unsigned)f2bf(b) << 16);
}

// ---------------------------------------------------------------- fused: psum-zero + partition + gemm1
// blocks [0,NC): level-1 edge partition; blocks [NC,NC+NGB): gemm1 64-row tile.
// gemm1 writes UNSCALED X@W1 (dis not ready yet); build_csr folds dis in.
__global__ __launch_bounds__(256) void prep_gemm(const int* __restrict__ ei,
                                                 int* __restrict__ histg,
                                                 int2* __restrict__ ebuf,
                                                 const float* __restrict__ X,
                                                 const float* __restrict__ W,
                                                 unsigned short* __restrict__ Y,
                                                 float* __restrict__ psum) {
    __shared__ __align__(16) char smem[35840];
    const int t = threadIdx.x;

    if (blockIdx.x < NC) {
        // ---------------- partition path ----------------
        int* hist = (int*)smem;
        int* incl = hist + 256;
        int* lcur = incl + 256;
        int2* lpairs = (int2*)(smem + 3072);
        const int c = blockIdx.x;
        const int c0 = c * CH;

        hist[t] = 0;
        __syncthreads();

        int2 loc[16];
#pragma unroll
        for (int j = 0; j < 16; ++j) {
            int e = c0 + j * 256 + t;
            int s = -1, d = -1;
            if (e < NE) {
                s = ei[e]; d = ei[NE + e];
                atomicAdd(&hist[d >> 8], 1);
            }
            loc[j] = make_int2(s, d);
        }
        __syncthreads();

        int v = hist[t];
        incl[t] = v;
        __syncthreads();
        for (int off = 1; off < 256; off <<= 1) {
            int u = (t >= off) ? incl[t - off] : 0;
            __syncthreads();
            incl[t] += u;
            __syncthreads();
        }
        lcur[t] = incl[t] - v;
        if (t < NB) histg[c * NB + t] = v;
        __syncthreads();

#pragma unroll
        for (int j = 0; j < 16; ++j) {
            int d = loc[j].y;
            if (d >= 0) {
                int p = atomicAdd(&lcur[d >> 8], 1);
                lpairs[p] = loc[j];
            }
        }
        __syncthreads();

        const int total = incl[255];
        for (int p = t; p < total; p += 256) {
            int2 pr = lpairs[p];
            int b = pr.y >> 8;
            int i = p - (incl[b] - hist[b]);
            ebuf[(b * NC + c) * CELL + i] = pr;
        }
    } else {
        // ---------------- gemm1 path (no dis dependency) ----------------
        const int gb = blockIdx.x - NC;
        if (gb < 16)   // zero psum
            *(float4*)&psum[gb * 1024 + t * 4] = make_float4(0.f, 0.f, 0.f, 0.f);

        unsigned short* Xs = (unsigned short*)smem;       // 64*136 bf16
        unsigned int* Wt = (unsigned int*)(smem + 17408); // 64*68 packed
        const int base = gb * 64;

        for (int i = t * 4; i < 64 * 128; i += 1024) {
            int node = i >> 7, k = i & 127;
            int gn = base + node; if (gn >= NN) gn = NN - 1;
            float4 v = *(const float4*)&X[(size_t)gn * 128 + k];
            ushort4 o = { f2bf(v.x), f2bf(v.y), f2bf(v.z), f2bf(v.w) };
            *(ushort4*)&Xs[node * 136 + k] = o;
        }
        for (int idx = t; idx < 64 * 64; idx += 256) {
            int n = idx & 63, kp = idx >> 6;
            float w0 = W[(2 * kp) * 64 + n];
            float w1 = W[(2 * kp + 1) * 64 + n];
            Wt[n * 68 + kp] = (unsigned)f2bf(w0) | ((unsigned)f2bf(w1) << 16);
        }
        __syncthreads();

        const int w = t >> 6;
        const int lane = t & 63;
        const int l15 = lane & 15;
        const int quad = lane >> 4;
        f32x4 acc[4] = {{0.f,0.f,0.f,0.f},{0.f,0.f,0.f,0.f},{0.f,0.f,0.f,0.f},{0.f,0.f,0.f,0.f}};
#pragma unroll
        for (int kk = 0; kk < 4; ++kk) {
            const bf16x8 a = *(const bf16x8*)&Xs[(w * 16 + l15) * 136 + quad * 8 + kk * 32];
#pragma unroll
            for (int nt = 0; nt < 4; ++nt) {
                const bf16x8 b = *(const bf16x8*)&Wt[(nt * 16 + l15) * 68 + quad * 4 + kk * 16];
                acc[nt] = __builtin_amdgcn_mfma_f32_16x16x32_bf16(a, b, acc[nt], 0, 0, 0);
            }
        }
        const int r0 = base + w * 16 + quad * 4;
#pragma unroll
        for (int reg = 0; reg < 4; ++reg) {
            const int row = r0 + reg;
            if (row < NN) {
#pragma unroll
                for (int nt = 0; nt < 4; ++nt)
                    Y[(size_t)row * 64 + nt * 16 + l15] = f2bf(acc[nt][reg]);
            }
        }
    }
}

// ---------------------------------------------------------------- level-2: per-bucket CSR + dis + fold dis into h
__global__ __launch_bounds__(256) void build_csr(const int2* __restrict__ ebuf,
                                                 const int* __restrict__ histg,
                                                 int2* __restrict__ row_range,
                                                 float* __restrict__ dis,
                                                 int* __restrict__ csr_src,
                                                 unsigned short* __restrict__ h) {
    const int b = blockIdx.x, t = threadIdx.x;
    const int e0 = b * CAP;
    const int node = b * 256 + t;
    __shared__ int coff[256];
    __shared__ int deg_l[256];
    __shared__ int pre[256];
    __shared__ int cur[256];
    __shared__ float sdis[256];
    __shared__ int2 lpairs[CAP];
    __shared__ int lsrc[CAP];

    int cv = (t < NB) ? histg[t * NB + b] : 0;
    coff[t] = cv;
    __syncthreads();
    for (int off = 1; off < 256; off <<= 1) {
        int u = (t >= off) ? coff[t - off] : 0;
        __syncthreads();
        coff[t] += u;
        __syncthreads();
    }
    if (cv > 0) {
        const int2* src = &ebuf[(b * NC + t) * CELL];
        int dst = coff[t] - cv;
        for (int i = 0; i < cv; ++i)
            lpairs[dst + i] = src[i];
    }
    deg_l[t] = (node < NN) ? 1 : 0;   // self-loop
    __syncthreads();

    const int total = coff[255];
    for (int i = t; i < total; i += 256)
        atomicAdd(&deg_l[lpairs[i].y & 255], 1);
    __syncthreads();

    int v = deg_l[t];
    pre[t] = v;
    __syncthreads();
    for (int off = 1; off < 256; off <<= 1) {
        int u = (t >= off) ? pre[t - off] : 0;
        __syncthreads();
        pre[t] += u;
        __syncthreads();
    }
    int excl = pre[t] - v;
    cur[t] = 1;                        // slot 0 = self-loop
    float dv = 0.f;
    if (node < NN) {
        lsrc[excl] = node;
        row_range[node] = make_int2(e0 + excl, e0 + pre[t]);
        dv = rsqrtf((float)v);         // v = deg+1
        dis[node] = dv;
    }
    sdis[t] = dv;
    __syncthreads();
    for (int i = t; i < total; i += 256) {
        int2 p = lpairs[i];
        int d = p.y & 255;
        int pos = (pre[d] - deg_l[d]) + atomicAdd(&cur[d], 1);
        lsrc[pos] = p.x;
    }
    __syncthreads();
    const int tot_all = pre[255];
    for (int i = t; i < tot_all; i += 256)
        csr_src[e0 + i] = lsrc[i];

    // fold dis into h rows (bufA written by prep_gemm, previous dispatch):
    // 8 lanes per row, 32 rows per pass — fully coalesced r/m/w.
    const int rl0 = t >> 3;
    const int d8 = (t & 7) * 8;
#pragma unroll
    for (int c = 0; c < 8; ++c) {
        const int rl = c * 32 + rl0;
        const int n2 = b * 256 + rl;
        if (n2 < NN) {
            const float dd = sdis[rl];
            uint4 u = *(uint4*)&h[(size_t)n2 * 64 + d8];
            uint4 o;
            o.x = pack2(lo16(u.x) * dd, hi16(u.x) * dd);
            o.y = pack2(lo16(u.y) * dd, hi16(u.y) * dd);
            o.z = pack2(lo16(u.z) * dd, hi16(u.z) * dd);
            o.w = pack2(lo16(u.w) * dd, hi16(u.w) * dd);
            *(uint4*)&h[(size_t)n2 * 64 + d8] = o;
        }
    }
}

// ---------------------------------------------------------------- sub-group gather core (pre-scaled rows, no dis)
static __device__ __forceinline__ void acc8(float* acc, const uint4 u) {
    acc[0] += lo16(u.x); acc[1] += hi16(u.x);
    acc[2] += lo16(u.y); acc[3] += hi16(u.y);
    acc[4] += lo16(u.z); acc[5] += hi16(u.z);
    acc[6] += lo16(u.w); acc[7] += hi16(u.w);
}

static __device__ __forceinline__ void gather_rows(const unsigned short* __restrict__ h,
                                                   const int* __restrict__ csr_src,
                                                   int lo, int hi, int p8, float* acc) {
    int i = lo;
    for (; i + 4 <= hi; i += 4) {
        const int i0 = csr_src[i];
        const int i1 = csr_src[i + 1];
        const int i2 = csr_src[i + 2];
        const int i3 = csr_src[i + 3];
        const uint4 u0 = *(const uint4*)&h[(i0 << 6) + p8];
        const uint4 u1 = *(const uint4*)&h[(i1 << 6) + p8];
        const uint4 u2 = *(const uint4*)&h[(i2 << 6) + p8];
        const uint4 u3 = *(const uint4*)&h[(i3 << 6) + p8];
        acc8(acc, u0); acc8(acc, u1); acc8(acc, u2); acc8(acc, u3);
    }
    for (; i + 2 <= hi; i += 2) {
        const int i0 = csr_src[i];
        const int i1 = csr_src[i + 1];
        const uint4 u0 = *(const uint4*)&h[(i0 << 6) + p8];
        const uint4 u1 = *(const uint4*)&h[(i1 << 6) + p8];
        acc8(acc, u0); acc8(acc, u1);
    }
    if (i < hi) {
        const int i0 = csr_src[i];
        acc8(acc, *(const uint4*)&h[(i0 << 6) + p8]);
    }
}

// ---------------------------------------------------------------- agg1 + gemm2 fused (MFMA phase 2)
// h rows pre-scaled by dis[src]; h1 = relu(dn*acc + b1); A = bf16(h1);
// bufB row = dis[row] * (A @ W2)  (pre-scaled for layer 2).
__global__ __launch_bounds__(256) void agg_gemv(const unsigned short* __restrict__ h,
                                                const int2* __restrict__ row_range,
                                                const int* __restrict__ csr_src,
                                                const float* __restrict__ dis,
                                                const float* __restrict__ b1,
                                                const float* __restrict__ W2,
                                                unsigned short* __restrict__ g) {
    __shared__ unsigned short W2b[64 * 72];  // [n][k] bf16
    __shared__ unsigned short A[32 * 72];    // [m=node][k=dim] bf16
    const int t = threadIdx.x;
    for (int idx = t; idx < 64 * 32; idx += 256) {
        int n = idx & 63, kp = idx >> 6;
        unsigned short w0 = f2bf(W2[(2 * kp) * 64 + n]);
        unsigned short w1 = f2bf(W2[(2 * kp + 1) * 64 + n]);
        *(unsigned*)&W2b[n * 72 + 2 * kp] = (unsigned)w0 | ((unsigned)w1 << 16);
    }

    const int base = blockIdx.x * 32;
    const int nloc = t >> 3;
    const int p8 = (t & 7) * 8;
    const int n = base + nloc;
    float acc[8] = {};
    if (n < NN) {
        const int2 rr = row_range[n];
        gather_rows(h, csr_src, rr.x, rr.y, p8, acc);
        const float dn = dis[n];
        const float4 bv0 = *(const float4*)&b1[p8];
        const float4 bv1 = *(const float4*)&b1[p8 + 4];
        acc[0] = fmaxf(acc[0] * dn + bv0.x, 0.f);
        acc[1] = fmaxf(acc[1] * dn + bv0.y, 0.f);
        acc[2] = fmaxf(acc[2] * dn + bv0.z, 0.f);
        acc[3] = fmaxf(acc[3] * dn + bv0.w, 0.f);
        acc[4] = fmaxf(acc[4] * dn + bv1.x, 0.f);
        acc[5] = fmaxf(acc[5] * dn + bv1.y, 0.f);
        acc[6] = fmaxf(acc[6] * dn + bv1.z, 0.f);
        acc[7] = fmaxf(acc[7] * dn + bv1.w, 0.f);
    }
    uint4 pk;
    pk.x = pack2(acc[0], acc[1]);
    pk.y = pack2(acc[2], acc[3]);
    pk.z = pack2(acc[4], acc[5]);
    pk.w = pack2(acc[6], acc[7]);
    *(uint4*)&A[nloc * 72 + p8] = pk;
    __syncthreads();

    const int w = t >> 6;
    const int lane = t & 63;
    const int l15 = lane & 15;
    const int quad = lane >> 4;
    const int mt = w & 1;
    const int nq = (w >> 1) * 2;
    const bf16x8 a0 = *(const bf16x8*)&A[(mt * 16 + l15) * 72 + quad * 8];
    const bf16x8 a1 = *(const bf16x8*)&A[(mt * 16 + l15) * 72 + 32 + quad * 8];
    const bf16x8 b00 = *(const bf16x8*)&W2b[(nq * 16 + l15) * 72 + quad * 8];
    const bf16x8 b01 = *(const bf16x8*)&W2b[(nq * 16 + l15) * 72 + 32 + quad * 8];
    const bf16x8 b10 = *(const bf16x8*)&W2b[((nq + 1) * 16 + l15) * 72 + quad * 8];
    const bf16x8 b11 = *(const bf16x8*)&W2b[((nq + 1) * 16 + l15) * 72 + 32 + quad * 8];
    f32x4 c0 = {0.f, 0.f, 0.f, 0.f}, c1 = {0.f, 0.f, 0.f, 0.f};
    c0 = __builtin_amdgcn_mfma_f32_16x16x32_bf16(a0, b00, c0, 0, 0, 0);
    c0 = __builtin_amdgcn_mfma_f32_16x16x32_bf16(a1, b01, c0, 0, 0, 0);
    c1 = __builtin_amdgcn_mfma_f32_16x16x32_bf16(a0, b10, c1, 0, 0, 0);
    c1 = __builtin_amdgcn_mfma_f32_16x16x32_bf16(a1, b11, c1, 0, 0, 0);
    const int r0 = base + mt * 16 + quad * 4;
    float4 d4 = *(const float4*)&dis[r0];   // tail over-read; stores guarded
    const float dd[4] = { d4.x, d4.y, d4.z, d4.w };
#pragma unroll
    for (int reg = 0; reg < 4; ++reg) {
        const int row = r0 + reg;
        if (row < NN) {
            g[(size_t)row * 64 + nq * 16 + l15] = f2bf(c0[reg] * dd[reg]);
            g[(size_t)row * 64 + (nq + 1) * 16 + l15] = f2bf(c1[reg] * dd[reg]);
        }
    }
}

// ---------------------------------------------------------------- agg2 + pooling fused
__global__ __launch_bounds__(256) void agg_pool(const unsigned short* __restrict__ h,
                                                const int2* __restrict__ row_range,
                                                const int* __restrict__ csr_src,
                                                const float* __restrict__ dis,
                                                const float* __restrict__ bias,
                                                const int* __restrict__ batch,
                                                float* __restrict__ psum) {
    __shared__ float rowsL[32 * 68];
    __shared__ int nb[32];
    const int t = threadIdx.x;
    const int nloc = t >> 3;
    const int n = blockIdx.x * 32 + nloc;
    const int p8 = (t & 7) * 8;
    if ((t & 7) == 0) nb[nloc] = (n < NN) ? batch[n] : -1;
    if (n < NN) {
        const int2 rr = row_range[n];
        float acc[8] = {};
        gather_rows(h, csr_src, rr.x, rr.y, p8, acc);
        const float dn = dis[n];
        const float4 bv0 = *(const float4*)&bias[p8];
        const float4 bv1 = *(const float4*)&bias[p8 + 4];
        float4 r0, r1;
        r0.x = fmaxf(acc[0] * dn + bv0.x, 0.f);
        r0.y = fmaxf(acc[1] * dn + bv0.y, 0.f);
        r0.z = fmaxf(acc[2] * dn + bv0.z, 0.f);
        r0.w = fmaxf(acc[3] * dn + bv0.w, 0.f);
        r1.x = fmaxf(acc[4] * dn + bv1.x, 0.f);
        r1.y = fmaxf(acc[5] * dn + bv1.y, 0.f);
        r1.z = fmaxf(acc[6] * dn + bv1.z, 0.f);
        r1.w = fmaxf(acc[7] * dn + bv1.w, 0.f);
        *(float4*)&rowsL[nloc * 68 + p8] = r0;
        *(float4*)&rowsL[nloc * 68 + p8 + 4] = r1;
    }
    __syncthreads();
    if (t < 64) {
        float s = 0.f; int curg = -2;
        for (int r = 0; r < 32; ++r) {
            const int gg = nb[r];                 // wave-uniform
            if (gg != curg) {
                if (curg >= 0) atomicAdd(&psum[curg * 64 + t], s);
                s = 0.f; curg = gg;
            }
            if (gg >= 0) s += rowsL[r * 68 + t];
        }
        if (curg >= 0) atomicAdd(&psum[curg * 64 + t], s);
    }
}

// ---------------------------------------------------------------- head: mean + MLP
__global__ __launch_bounds__(64) void head_kernel(const float* __restrict__ psum,
                                                  const int* __restrict__ batch,
                                                  const float* __restrict__ Wm1,
                                                  const float* __restrict__ bm1,
                                                  const float* __restrict__ Wm2,
                                                  const float* __restrict__ bm2,
                                                  float* __restrict__ out) {
    const int g = blockIdx.x;
    const int t = threadIdx.x;
    int lo = 0, hi = NN;
    while (lo < hi) { int m = (lo + hi) >> 1; if (batch[m] < g) lo = m + 1; else hi = m; }
    const int s = lo;
    hi = NN;
    while (lo < hi) { int m = (lo + hi) >> 1; if (batch[m] < g + 1) lo = m + 1; else hi = m; }
    const int cnt = lo - s;

    __shared__ float pl[64];
    pl[t] = psum[g * 64 + t] / (float)(cnt > 0 ? cnt : 1);
    __syncthreads();
    float z = bm1[t];
#pragma unroll 8
    for (int k = 0; k < 64; ++k)
        z += pl[k] * Wm1[k * 64 + t];
    z = fmaxf(z, 0.f);
    float y = z * Wm2[t];
    for (int off = 32; off; off >>= 1) y += __shfl_down(y, off);
    if (t == 0) out[g] = y + bm2[0];
}

// ---------------------------------------------------------------- launch
extern "C" void kernel_launch(void* const* d_in, const int* in_sizes, int n_in,
                              void* d_out, int out_size, void* d_ws, size_t ws_size,
                              hipStream_t stream) {
    const float* x   = (const float*)d_in[0];
    const int*   ei  = (const int*)d_in[1];
    const int*   bat = (const int*)d_in[2];
    const float* W1  = (const float*)d_in[3];
    const float* b1  = (const float*)d_in[4];
    const float* W2  = (const float*)d_in[5];
    const float* b2  = (const float*)d_in[6];
    const float* Wm1 = (const float*)d_in[7];
    const float* bm1 = (const float*)d_in[8];
    const float* Wm2 = (const float*)d_in[9];
    const float* bm2 = (const float*)d_in[10];
    float* out = (float*)d_out;

    char* w = (char*)d_ws;
    int*            histg     = (int*)           (w + 0);          //   153664 B
    int2*           row_range = (int2*)          (w + 153664);     //   400000 B
    float*          dis       = (float*)         (w + 553664);     //   200000 B
    int*            csr_src   = (int*)           (w + 753664);     //  4014080 B
    int2*           ebuf      = (int2*)          (w + 4767744);    // 24586240 B
    unsigned short* bufA      = (unsigned short*)(w + 29353984);   //  6400000 B
    unsigned short* bufB      = (unsigned short*)(w + 35753984);   //  6400000 B
    float*          psum      = (float*)         (w + 42153984);   //    65536 B

    prep_gemm <<<NC + NGB, 256, 0, stream>>>(ei, histg, ebuf, x, W1, bufA, psum);
    build_csr <<<NB, 256, 0, stream>>>(ebuf, histg, row_range, dis, csr_src, bufA);
    agg_gemv  <<<(NN + 31) / 32, 256, 0, stream>>>(bufA, row_range, csr_src, dis, b1, W2, bufB);
    agg_pool  <<<(NN + 31) / 32, 256, 0, stream>>>(bufB, row_range, csr_src, dis, b2, bat, psum);
    head_kernel<<<NG, 64, 0, stream>>>(psum, bat, Wm1, bm1, Wm2, bm2, out);
}